// Round 2
// 223.342 us; speedup vs baseline: 1.1722x; 1.1722x over previous
//
#include <hip/hip_runtime.h>

// Problem constants (match setup_inputs in the reference)
#define B_   16
#define R_   16
#define T_   4
#define S_   14
#define NPRB 273
#define NPD  6      // pilots per DMRS symbol per PRB (subcarrier positions)
#define NDS  2      // number of DMRS OFDM symbols
#define RE_  12     // resource elements per PRB
#define P_   (NDS*NPRB*NPD)   // 3276 pilots total
#define NSC  (NPRB*RE_)       // 3276 subcarriers
#define F_   (RE_*S_)         // 168 grid positions per tx

#define NH   (B_*T_*NSC*S_*R_)   // 46964736 floats (h_full)
#define NPE  (T_*NSC*S_*2)       // 366912 floats (pe)
#define NH4  (NH/4)
#define NPE4 (NPE/4)             // 91728 float4

#define CHUNK4   (RE_*S_*R_/4)   // 672 float4 per (b,t,prb) output chunk
#define NBLK_PE  ((NPE4 + 255)/256)   // 359 blocks for pe
#define NBLK_H   (B_*T_*NPRB)         // 17472 blocks for h_full

// Native 16B vector type (HIP's float4 class is rejected by
// __builtin_nontemporal_store; ext_vector_type is accepted and supports
// elementwise arithmetic directly).
typedef float f4 __attribute__((ext_vector_type(4)));

// Single fused kernel.
//  - pe blocks (bid < NBLK_PE): rebuild the tiny per-tx distance tables +
//    mean/std (ddof=1) locally, write pe.  (~1.5 MB total; replaces prep_tables)
//  - h blocks: one block per (b,t,prb).  Stage the 12 pilots' FOCC-averaged
//    values in LDS (each h_hat_ls float is read from HBM exactly once chip-wide),
//    build a pre-permuted code table, then stream 672 coalesced nontemporal
//    float4 stores.
__global__ __launch_bounds__(256) void fused_kernel(
    const float* __restrict__ hls,      // h_hat_ls [B_, P_, T_, R_]
    const int* __restrict__ ofdm_pos,   // [T_, NDS]
    const int* __restrict__ sc_pos,     // [T_, NPD]
    float* __restrict__ out)            // h_full (NH) then pe (NPE)
{
    const int bid = blockIdx.x;
    const int tid = threadIdx.x;

    if (bid >= NBLK_PE) {
        // ---------------- h_full path ----------------
        __shared__ int perm_sh[F_];    // code per v = kl*S_ + s  (pre-permuted)
        __shared__ f4  avg_sh[6*4];    // [code 0..5][r4] FOCC-averaged pilots

        const int hb  = bid - NBLK_PE;
        const int prb = hb % NPRB;
        const int bt  = hb / NPRB;         // b*T_ + t
        const int t   = bt & (T_-1);

        if (tid < F_) {
            // Build code table, already permuted to the output's v-order.
            // v = kl*S_ + s; the reference's scrambled table index is
            // j' = s*RE_ + kl, whose flat (re-major) decode is (j'/S_, j'%S_).
            const int v  = tid;
            const int kl = v / S_, s = v - (v / S_)*S_;
            const int jp = s*RE_ + kl;
            const int rej = jp / S_, sj = jp - (jp / S_)*S_;
            int best = 1 << 30, bestj = 0;
            for (int sci = 0; sci < NPD; ++sci) {
                const int dsc = abs(rej - sc_pos[t*NPD + sci]);
                for (int ofi = 0; ofi < NDS; ++ofi) {
                    const int dof = abs(sj - ofdm_pos[t*NDS + ofi]);
                    const int d = dsc + dof;
                    // strict < keeps FIRST minimum == jnp.argmin tie-break
                    if (d < best) { best = d; bestj = sci*NDS + ofi; }
                }
            }
            // bestj = sci*2+ofi: ds = bestj&1, sc0/2 = bestj>>2
            perm_sh[v] = (bestj & 1)*3 + (bestj >> 2);
        } else if (tid >= 192 && tid < 216) {
            // Stage FOCC-averaged pilot pairs: 24 threads, 2 f4 loads each.
            const int j    = tid - 192;          // [0,24)
            const int code = j >> 2, r4 = j & 3; // code = ds*3 + sc0/2
            const int ds   = (code >= 3) ? 1 : 0;
            const int scp  = code - 3*ds;
            const int b    = bt >> 2;
            const int p0   = ds*(NPRB*NPD) + prb*NPD + 2*scp; // even FOCC member
            const f4* src = (const f4*)hls + ((b*P_ + p0)*T_ + t)*4 + r4;
            const f4 a = src[0];
            const f4 c = src[T_*4];              // pilot p0+1: +T_*R_ floats
            avg_sh[j] = 0.5f*(a + c);
        }
        __syncthreads();

        // Output chunk for (b,t,prb) is contiguous: 672 f4.
        f4* out4 = (f4*)out + (size_t)bt*(NSC*S_*R_/4) + (size_t)prb*CHUNK4;
        #pragma unroll
        for (int u = tid; u < CHUNK4; u += 256) {
            const int r4 = u & 3;
            const int v  = u >> 2;
            const int code = perm_sh[v];
            __builtin_nontemporal_store(avg_sh[code*4 + r4], &out4[u]);
        }
    } else {
        // ---------------- pe path ----------------
        __shared__ float dt_sh[T_*F_];
        __shared__ float df_sh[T_*F_];
        __shared__ float stats[T_][4]; // mean_t, inv_std_t, mean_f, inv_std_f

        for (int e = tid; e < T_*F_; e += 256) {
            const int t  = e / F_, j = e - (e / F_)*F_;
            const int rej = j / S_, sj = j - (j / S_)*S_;
            int dfmin = 1 << 30, dtmin = 1 << 30;
            for (int sci = 0; sci < NPD; ++sci) {
                const int dsc = abs(rej - sc_pos[t*NPD + sci]);
                if (dsc < dfmin) dfmin = dsc;
            }
            for (int ofi = 0; ofi < NDS; ++ofi) {
                const int dof = abs(sj - ofdm_pos[t*NDS + ofi]);
                if (dof < dtmin) dtmin = dof;
            }
            dt_sh[e] = (float)dtmin;
            df_sh[e] = (float)dfmin;
        }
        __syncthreads();

        // 256 threads = 4 waves; wave w reduces tx t=w.
        const int w = tid >> 6, lane = tid & 63;
        {
            float sdt = 0.f, sdf = 0.f;
            for (int j = lane; j < F_; j += 64) { sdt += dt_sh[w*F_+j]; sdf += df_sh[w*F_+j]; }
            for (int o = 32; o > 0; o >>= 1) { sdt += __shfl_down(sdt, o); sdf += __shfl_down(sdf, o); }
            if (lane == 0) { stats[w][0] = sdt/(float)F_; stats[w][2] = sdf/(float)F_; }
        }
        __syncthreads();
        {
            const float mt = stats[w][0], mf = stats[w][2];
            float vt = 0.f, vf = 0.f;
            for (int j = lane; j < F_; j += 64) {
                const float a = dt_sh[w*F_+j] - mt; vt += a*a;
                const float b = df_sh[w*F_+j] - mf; vf += b*b;
            }
            for (int o = 32; o > 0; o >>= 1) { vt += __shfl_down(vt, o); vf += __shfl_down(vf, o); }
            if (lane == 0) {
                stats[w][1] = 1.0f/(sqrtf(vt/(float)(F_-1)) + 1e-8f);  // ddof=1
                stats[w][3] = 1.0f/(sqrtf(vf/(float)(F_-1)) + 1e-8f);
            }
        }
        __syncthreads();

        const int q = bid*256 + tid;    // f4 index into pe
        if (q < NPE4) {
            const int g0 = q*4;
            float vv[4];
            #pragma unroll
            for (int u2 = 0; u2 < 4; ++u2) {
                // pe flat index = ((t*NSC + i)*S_ + s)*2 + c
                const int g  = g0 + u2;
                const int c  = g & 1;
                const int g1 = g >> 1;
                const int s  = g1 % S_;
                const int g2 = g1 / S_;
                const int i  = g2 % NSC;
                const int t  = g2 / NSC;
                const int re = i % RE_;
                const int j  = s*RE_ + re;    // reference's scrambled lookup
                const float d = (c == 0) ? dt_sh[t*F_ + j] : df_sh[t*F_ + j];
                vv[u2] = (d - stats[t][2*c]) * stats[t][2*c + 1];
            }
            f4 o; o.x = vv[0]; o.y = vv[1]; o.z = vv[2]; o.w = vv[3];
            __builtin_nontemporal_store(o, (f4*)(out + NH) + q);
        }
    }
}

extern "C" void kernel_launch(void* const* d_in, const int* in_sizes, int n_in,
                              void* d_out, int out_size, void* d_ws, size_t ws_size,
                              hipStream_t stream) {
    // inputs: y (unused, shape only), h_hat_ls f32, dmrs_ofdm_pos i32, dmrs_subcarrier_pos i32
    const float* hls  = (const float*)d_in[1];
    const int*   ofdm = (const int*)d_in[2];
    const int*   scp  = (const int*)d_in[3];
    float* out = (float*)d_out;

    hipLaunchKernelGGL(fused_kernel, dim3(NBLK_PE + NBLK_H), dim3(256), 0, stream,
                       hls, ofdm, scp, out);
}